// Round 1
// baseline (703.378 us; speedup 1.0000x reference)
//
#include <hip/hip_runtime.h>
#include <math.h>

#define BB 32
#define CC 512
#define NN 4096
#define EMB 1024
#define NH 16

// d_out layout (floats): values | pos | batch | attention | penalty
#define OFF_POS   (BB*NH*EMB)             // 524288
#define OFF_BATCH (OFF_POS + BB*NH*2)     // 525312
#define OFF_ATTN  (OFF_BATCH + BB*NH)     // 525824
#define OFF_PEN   (OFF_ATTN + BB*NN*NH)   // 2622976

// ---------------- Kernel 1: x_mean[b,c] = mean over N of x[b,c,:] ----------------
__global__ __launch_bounds__(256) void k_mean(const float* __restrict__ x,
                                              float* __restrict__ xmean) {
    const size_t row = blockIdx.x;            // b*CC + c
    const float4* xr = (const float4*)(x + row * NN);
    const int t = threadIdx.x;
    float s = 0.f;
#pragma unroll
    for (int k = 0; k < 4; ++k) {
        float4 v = xr[t + 256 * k];
        s += (v.x + v.y) + (v.z + v.w);
    }
#pragma unroll
    for (int off = 32; off > 0; off >>= 1) s += __shfl_down(s, off, 64);
    __shared__ float ps[4];
    if ((t & 63) == 0) ps[t >> 6] = s;
    __syncthreads();
    if (t == 0) xmean[row] = (ps[0] + ps[1] + ps[2] + ps[3]) * (1.0f / NN);
}

// ---------------- Kernel 2: MLP -> pos (written to d_out pos region) ----------------
__global__ __launch_bounds__(256) void k_mlp(const float* __restrict__ xmean,
                                             const float* __restrict__ w1,
                                             const float* __restrict__ b1,
                                             const float* __restrict__ w2,
                                             const float* __restrict__ b2,
                                             float* __restrict__ out) {
    const int b = blockIdx.x;
    const int t = threadIdx.x;
    __shared__ __align__(16) float xm[CC];
    __shared__ __align__(16) float hid[EMB];
    xm[t]       = xmean[b * CC + t];
    xm[t + 256] = xmean[b * CC + t + 256];
    __syncthreads();
#pragma unroll
    for (int eo = 0; eo < 4; ++eo) {
        const int e = t + eo * 256;
        const float4* wr = (const float4*)(w1 + (size_t)e * CC);
        const float4* xv = (const float4*)xm;
        float acc = 0.f;
        for (int c4 = 0; c4 < CC / 4; ++c4) {
            float4 w = wr[c4]; float4 xx = xv[c4];
            acc += w.x * xx.x + w.y * xx.y + w.z * xx.z + w.w * xx.w;
        }
        acc += b1[e];
        hid[e] = acc / (1.f + expf(-acc));   // silu
    }
    __syncthreads();
    if (t < 2 * NH) {
        const float4* wr = (const float4*)(w2 + (size_t)t * EMB);
        const float4* hv = (const float4*)hid;
        float acc = 0.f;
        for (int e4 = 0; e4 < EMB / 4; ++e4) {
            float4 w = wr[e4]; float4 hh = hv[e4];
            acc += w.x * hh.x + w.y * hh.y + w.z * hh.z + w.w * hh.w;
        }
        acc += b2[t];
        out[OFF_POS + b * 2 * NH + t] = 31.f / (1.f + expf(-acc));  // 31*sigmoid
    }
}

// ---------------- Kernel 3: attention + pen ----------------
__global__ __launch_bounds__(256) void k_attn(float* __restrict__ out,
                                              float* __restrict__ pen) {
    const int b = blockIdx.y;
    const int n0 = blockIdx.x * 256;
    const int t = threadIdx.x;
    __shared__ float pp[2 * NH];
    if (t < 2 * NH) pp[t] = out[OFF_POS + b * 2 * NH + t];
    __syncthreads();
    const int n = n0 + t;
    const float fi = (float)(n >> 6);
    const float fj = (float)(n & 63);
    const float norm = 0.017683882565766149f;   // 1/(2*pi*9)
    float a[NH];
#pragma unroll
    for (int h = 0; h < NH; ++h) {
        float dx = fi - pp[2 * h];
        float dy = fj - pp[2 * h + 1];
        a[h] = norm * expf((dx * dx + dy * dy) * (-1.f / 18.f));
    }
    float4* dst = (float4*)(out + OFF_ATTN + ((size_t)b * NN + n) * NH);
#pragma unroll
    for (int q = 0; q < 4; ++q)
        dst[q] = make_float4(a[4 * q], a[4 * q + 1], a[4 * q + 2], a[4 * q + 3]);
#pragma unroll
    for (int h = 0; h < NH; ++h) {
        float s = a[h];
#pragma unroll
        for (int off = 32; off > 0; off >>= 1) s += __shfl_down(s, off, 64);
        if ((t & 63) == 0) atomicAdd(&pen[b * NH + h], s);
    }
}

// ---------------- Kernel 4: S[b,h,c] += sum_n attn[b,n,h] * x[b,c,n] ----------------
__global__ __launch_bounds__(512) void k_S(const float* __restrict__ x,
                                           const float* __restrict__ out,
                                           float* __restrict__ S) {
    const int b = blockIdx.y;
    const int n0 = blockIdx.x * 256;
    const int t = threadIdx.x;
    __shared__ __align__(16) float al[256][NH];   // 16 KB, reads are wave-broadcast
    {
        const float4* src = (const float4*)(out + OFF_ATTN + ((size_t)b * NN + n0) * NH);
        float4* dst = (float4*)&al[0][0];
        dst[t]       = src[t];
        dst[t + 512] = src[t + 512];
    }
    __syncthreads();
    const int hg = t >> 7;          // 4 head-groups of 4 heads (uniform per wave)
    const int cs = (t >> 6) & 1;    // channel half
    const int lane = t & 63;
    float acc[4][4];
#pragma unroll
    for (int i = 0; i < 4; ++i)
#pragma unroll
        for (int h = 0; h < 4; ++h) acc[i][h] = 0.f;
    const float* xb = x + (size_t)b * CC * NN + n0;
#pragma unroll 1
    for (int nb = 0; nb < 256; nb += 4) {
        float4 av[4];
#pragma unroll
        for (int k = 0; k < 4; ++k) av[k] = *(const float4*)&al[nb + k][hg * 4];
#pragma unroll
        for (int i = 0; i < 4; ++i) {
            const int c = lane + 64 * (cs * 4 + i);
            float4 xv = *(const float4*)(xb + (size_t)c * NN + nb);
            acc[i][0] += xv.x * av[0].x + xv.y * av[1].x + xv.z * av[2].x + xv.w * av[3].x;
            acc[i][1] += xv.x * av[0].y + xv.y * av[1].y + xv.z * av[2].y + xv.w * av[3].y;
            acc[i][2] += xv.x * av[0].z + xv.y * av[1].z + xv.z * av[2].z + xv.w * av[3].z;
            acc[i][3] += xv.x * av[0].w + xv.y * av[1].w + xv.z * av[2].w + xv.w * av[3].w;
        }
    }
#pragma unroll
    for (int i = 0; i < 4; ++i) {
        const int c = lane + 64 * (cs * 4 + i);
#pragma unroll
        for (int h = 0; h < 4; ++h)
            atomicAdd(&S[(size_t)(b * NH + hg * 4 + h) * CC + c], acc[i][h]);
    }
}

// ---------------- Kernel 5: values = S @ wv^T + pen*bv ----------------
__global__ __launch_bounds__(256) void k_gemm(const float* __restrict__ S,
                                              const float* __restrict__ wv,
                                              const float* __restrict__ bv,
                                              const float* __restrict__ pen,
                                              float* __restrict__ out) {
    const int m0 = blockIdx.x * 64;   // over B*NH = 512
    const int n0 = blockIdx.y * 64;   // over EMB = 1024
    const int t = threadIdx.x;
    const int tx = t & 15, ty = t >> 4;
    __shared__ float As[64][33];
    __shared__ float Bs[64][33];
    float acc[4][4];
#pragma unroll
    for (int mi = 0; mi < 4; ++mi)
#pragma unroll
        for (int ni = 0; ni < 4; ++ni) acc[mi][ni] = 0.f;
    for (int k0 = 0; k0 < CC; k0 += 32) {
#pragma unroll
        for (int l = 0; l < 2; ++l) {
            const int fi = t + l * 256;
            const int row = fi >> 3, c4 = (fi & 7) * 4;
            float4 va = *(const float4*)(S + (size_t)(m0 + row) * CC + k0 + c4);
            As[row][c4] = va.x; As[row][c4+1] = va.y; As[row][c4+2] = va.z; As[row][c4+3] = va.w;
            float4 vb = *(const float4*)(wv + (size_t)(n0 + row) * CC + k0 + c4);
            Bs[row][c4] = vb.x; Bs[row][c4+1] = vb.y; Bs[row][c4+2] = vb.z; Bs[row][c4+3] = vb.w;
        }
        __syncthreads();
#pragma unroll
        for (int k = 0; k < 32; ++k) {
            float a[4], bb[4];
#pragma unroll
            for (int mi = 0; mi < 4; ++mi) a[mi] = As[ty + 16 * mi][k];
#pragma unroll
            for (int ni = 0; ni < 4; ++ni) bb[ni] = Bs[tx + 16 * ni][k];
#pragma unroll
            for (int mi = 0; mi < 4; ++mi)
#pragma unroll
                for (int ni = 0; ni < 4; ++ni) acc[mi][ni] += a[mi] * bb[ni];
        }
        __syncthreads();
    }
#pragma unroll
    for (int mi = 0; mi < 4; ++mi) {
        const int m = m0 + ty + 16 * mi;
        const float pm = pen[m];
#pragma unroll
        for (int ni = 0; ni < 4; ++ni) {
            const int nn = n0 + tx + 16 * ni;
            out[(size_t)m * EMB + nn] = acc[mi][ni] + pm * bv[nn];
        }
    }
}

// ---------------- Kernel 6: penalty + batch ----------------
__global__ __launch_bounds__(256) void k_final(const float* __restrict__ pen,
                                               float* __restrict__ out) {
    const int t = threadIdx.x;
    float s = 0.f;
#pragma unroll
    for (int r = 0; r < 2; ++r) {
        const int i = t + 256 * r;
        float d = pen[i] - 1.f;
        s += d * d;
        out[OFF_BATCH + i] = (float)(i >> 4);
    }
#pragma unroll
    for (int off = 32; off > 0; off >>= 1) s += __shfl_down(s, off, 64);
    __shared__ float ps[4];
    if ((t & 63) == 0) ps[t >> 6] = s;
    __syncthreads();
    if (t == 0) out[OFF_PEN] = (ps[0] + ps[1] + ps[2] + ps[3]) * (1.f / 512.f);
}

extern "C" void kernel_launch(void* const* d_in, const int* in_sizes, int n_in,
                              void* d_out, int out_size, void* d_ws, size_t ws_size,
                              hipStream_t stream) {
    const float* x  = (const float*)d_in[0];
    const float* w1 = (const float*)d_in[1];
    const float* b1 = (const float*)d_in[2];
    const float* w2 = (const float*)d_in[3];
    const float* b2 = (const float*)d_in[4];
    const float* wv = (const float*)d_in[5];
    const float* bv = (const float*)d_in[6];
    float* out = (float*)d_out;

    float* xmean = (float*)d_ws;          // BB*CC
    float* pen   = xmean + BB * CC;       // BB*NH
    float* S     = pen + BB * NH;         // BB*NH*CC

    // zero the atomic accumulators (pen + S)
    hipMemsetAsync(pen, 0, (size_t)(BB * NH + BB * NH * CC) * sizeof(float), stream);

    k_mean<<<BB * CC, 256, 0, stream>>>(x, xmean);
    k_mlp<<<BB, 256, 0, stream>>>(xmean, w1, b1, w2, b2, out);
    k_attn<<<dim3(NN / 256, BB), 256, 0, stream>>>(out, pen);
    k_S<<<dim3(NN / 256, BB), 512, 0, stream>>>(x, out, S);
    k_gemm<<<dim3(8, 16), 256, 0, stream>>>(S, wv, bv, pen, out);
    k_final<<<1, 256, 0, stream>>>(pen, out);
}

// Round 2
// 273.545 us; speedup vs baseline: 2.5713x; 2.5713x over previous
//
#include <hip/hip_runtime.h>
#include <math.h>

#define BB 32
#define CC 512
#define NN 4096
#define EMB 1024
#define NH 16

// d_out layout (floats): values | pos | batch | attention | penalty
#define OFF_POS   (BB*NH*EMB)             // 524288
#define OFF_BATCH (OFF_POS + BB*NH*2)     // 525312
#define OFF_ATTN  (OFF_BATCH + BB*NH)     // 525824
#define OFF_PEN   (OFF_ATTN + BB*NN*NH)   // 2622976

// ---------------- Kernel 1: x_mean[b,c] = mean over N of x[b,c,:] ----------------
__global__ __launch_bounds__(256) void k_mean(const float* __restrict__ x,
                                              float* __restrict__ xmean) {
    const size_t row = blockIdx.x;            // b*CC + c
    const float4* xr = (const float4*)(x + row * NN);
    const int t = threadIdx.x;
    float s = 0.f;
#pragma unroll
    for (int k = 0; k < 4; ++k) {
        float4 v = xr[t + 256 * k];
        s += (v.x + v.y) + (v.z + v.w);
    }
#pragma unroll
    for (int off = 32; off > 0; off >>= 1) s += __shfl_down(s, off, 64);
    __shared__ float ps[4];
    if ((t & 63) == 0) ps[t >> 6] = s;
    __syncthreads();
    if (t == 0) xmean[row] = (ps[0] + ps[1] + ps[2] + ps[3]) * (1.0f / NN);
}

// ---------------- Kernel 2: MLP -> pos (written to d_out pos region) ----------------
__global__ __launch_bounds__(256) void k_mlp(const float* __restrict__ xmean,
                                             const float* __restrict__ w1,
                                             const float* __restrict__ b1,
                                             const float* __restrict__ w2,
                                             const float* __restrict__ b2,
                                             float* __restrict__ out) {
    const int b = blockIdx.x;
    const int t = threadIdx.x;
    __shared__ __align__(16) float xm[CC];
    __shared__ __align__(16) float hid[EMB];
    xm[t]       = xmean[b * CC + t];
    xm[t + 256] = xmean[b * CC + t + 256];
    __syncthreads();
#pragma unroll
    for (int eo = 0; eo < 4; ++eo) {
        const int e = t + eo * 256;
        const float4* wr = (const float4*)(w1 + (size_t)e * CC);
        const float4* xv = (const float4*)xm;
        float acc = 0.f;
        for (int c4 = 0; c4 < CC / 4; ++c4) {
            float4 w = wr[c4]; float4 xx = xv[c4];
            acc += w.x * xx.x + w.y * xx.y + w.z * xx.z + w.w * xx.w;
        }
        acc += b1[e];
        hid[e] = acc / (1.f + expf(-acc));   // silu
    }
    __syncthreads();
    if (t < 2 * NH) {
        const float4* wr = (const float4*)(w2 + (size_t)t * EMB);
        const float4* hv = (const float4*)hid;
        float acc = 0.f;
        for (int e4 = 0; e4 < EMB / 4; ++e4) {
            float4 w = wr[e4]; float4 hh = hv[e4];
            acc += w.x * hh.x + w.y * hh.y + w.z * hh.z + w.w * hh.w;
        }
        acc += b2[t];
        out[OFF_POS + b * 2 * NH + t] = 31.f / (1.f + expf(-acc));  // 31*sigmoid
    }
}

// ---------------- Kernel 3: attention + pen ----------------
__global__ __launch_bounds__(256) void k_attn(float* __restrict__ out,
                                              float* __restrict__ pen) {
    const int b = blockIdx.y;
    const int n0 = blockIdx.x * 256;
    const int t = threadIdx.x;
    __shared__ float pp[2 * NH];
    if (t < 2 * NH) pp[t] = out[OFF_POS + b * 2 * NH + t];
    __syncthreads();
    const int n = n0 + t;
    const float fi = (float)(n >> 6);
    const float fj = (float)(n & 63);
    const float norm = 0.017683882565766149f;   // 1/(2*pi*9)
    float a[NH];
#pragma unroll
    for (int h = 0; h < NH; ++h) {
        float dx = fi - pp[2 * h];
        float dy = fj - pp[2 * h + 1];
        a[h] = norm * expf((dx * dx + dy * dy) * (-1.f / 18.f));
    }
    float4* dst = (float4*)(out + OFF_ATTN + ((size_t)b * NN + n) * NH);
#pragma unroll
    for (int q = 0; q < 4; ++q)
        dst[q] = make_float4(a[4 * q], a[4 * q + 1], a[4 * q + 2], a[4 * q + 3]);
#pragma unroll
    for (int h = 0; h < NH; ++h) {
        float s = a[h];
#pragma unroll
        for (int off = 32; off > 0; off >>= 1) s += __shfl_down(s, off, 64);
        if ((t & 63) == 0) atomicAdd(&pen[b * NH + h], s);
    }
}

// ---------------- Kernel 4: S[b,h,c] = sum_n attn[b,n,h] * x[b,c,n] ----------------
// lane -> n (coalesced x reads); wave -> 4 channels x 16 heads in registers;
// block = (b, 16-channel chunk) over full n; attn chunk staged transposed in LDS.
__global__ __launch_bounds__(256, 4) void k_S2(const float* __restrict__ x,
                                               const float* __restrict__ out,
                                               float* __restrict__ S) {
    // XCD swizzle: cluster the 32 same-b blocks onto one XCD for attn L2 reuse
    const int hwid = blockIdx.x;                 // 0..1023
    const int wgid = (hwid & 7) * 128 + (hwid >> 3);
    const int b  = wgid >> 5;
    const int c0 = (wgid & 31) * 16;
    const int t = threadIdx.x;
    const int w = t >> 6, lane = t & 63;
    const int cbase = c0 + w * 4;

    __shared__ float aT[NH][260];                // transposed attn chunk, pad 4

    float acc[4][NH];
#pragma unroll
    for (int i = 0; i < 4; ++i)
#pragma unroll
        for (int h = 0; h < NH; ++h) acc[i][h] = 0.f;

    const float* xb = x + ((size_t)b * CC + cbase) * NN;
    const float4* asrc = (const float4*)(out + OFF_ATTN + (size_t)b * NN * NH);

    for (int nc = 0; nc < 16; ++nc) {
        const int n0 = nc * 256;
        __syncthreads();                         // aT reuse guard
        // stage attn[n0:n0+256][16] -> aT[h][n] (transposed)
#pragma unroll
        for (int k = 0; k < 4; ++k) {
            const int i = t + 256 * k;           // float4 index within chunk
            float4 v = asrc[n0 * 4 + i];
            const int n = i >> 2, h0 = (i & 3) * 4;
            aT[h0][n] = v.x; aT[h0 + 1][n] = v.y; aT[h0 + 2][n] = v.z; aT[h0 + 3][n] = v.w;
        }
        __syncthreads();
        float4 xv[4];
#pragma unroll
        for (int i = 0; i < 4; ++i)
            xv[i] = *(const float4*)(xb + (size_t)i * NN + n0 + 4 * lane);
#pragma unroll
        for (int h = 0; h < NH; ++h) {
            float4 a = *(const float4*)&aT[h][4 * lane];
#pragma unroll
            for (int i = 0; i < 4; ++i)
                acc[i][h] += a.x * xv[i].x + a.y * xv[i].y + a.z * xv[i].z + a.w * xv[i].w;
        }
    }
    // cross-lane reduction over n
#pragma unroll
    for (int i = 0; i < 4; ++i)
#pragma unroll
        for (int h = 0; h < NH; ++h) {
            float s = acc[i][h];
#pragma unroll
            for (int off = 32; off > 0; off >>= 1) s += __shfl_down(s, off, 64);
            acc[i][h] = s;
        }
    if (lane == 0) {
#pragma unroll
        for (int i = 0; i < 4; ++i)
#pragma unroll
            for (int h = 0; h < NH; ++h)
                S[((size_t)b * NH + h) * CC + cbase + i] = acc[i][h];
    }
}

// ---------------- Kernel 5: values = S @ wv^T + pen*bv ----------------
__global__ __launch_bounds__(256) void k_gemm(const float* __restrict__ S,
                                              const float* __restrict__ wv,
                                              const float* __restrict__ bv,
                                              const float* __restrict__ pen,
                                              float* __restrict__ out) {
    const int m0 = blockIdx.x * 64;   // over B*NH = 512
    const int n0 = blockIdx.y * 64;   // over EMB = 1024
    const int t = threadIdx.x;
    const int tx = t & 15, ty = t >> 4;
    __shared__ float As[64][33];
    __shared__ float Bs[64][33];
    float acc[4][4];
#pragma unroll
    for (int mi = 0; mi < 4; ++mi)
#pragma unroll
        for (int ni = 0; ni < 4; ++ni) acc[mi][ni] = 0.f;
    for (int k0 = 0; k0 < CC; k0 += 32) {
#pragma unroll
        for (int l = 0; l < 2; ++l) {
            const int fi = t + l * 256;
            const int row = fi >> 3, c4 = (fi & 7) * 4;
            float4 va = *(const float4*)(S + (size_t)(m0 + row) * CC + k0 + c4);
            As[row][c4] = va.x; As[row][c4+1] = va.y; As[row][c4+2] = va.z; As[row][c4+3] = va.w;
            float4 vb = *(const float4*)(wv + (size_t)(n0 + row) * CC + k0 + c4);
            Bs[row][c4] = vb.x; Bs[row][c4+1] = vb.y; Bs[row][c4+2] = vb.z; Bs[row][c4+3] = vb.w;
        }
        __syncthreads();
#pragma unroll
        for (int k = 0; k < 32; ++k) {
            float a[4], bb[4];
#pragma unroll
            for (int mi = 0; mi < 4; ++mi) a[mi] = As[ty + 16 * mi][k];
#pragma unroll
            for (int ni = 0; ni < 4; ++ni) bb[ni] = Bs[tx + 16 * ni][k];
#pragma unroll
            for (int mi = 0; mi < 4; ++mi)
#pragma unroll
                for (int ni = 0; ni < 4; ++ni) acc[mi][ni] += a[mi] * bb[ni];
        }
        __syncthreads();
    }
#pragma unroll
    for (int mi = 0; mi < 4; ++mi) {
        const int m = m0 + ty + 16 * mi;
        const float pm = pen[m];
#pragma unroll
        for (int ni = 0; ni < 4; ++ni) {
            const int nn = n0 + tx + 16 * ni;
            out[(size_t)m * EMB + nn] = acc[mi][ni] + pm * bv[nn];
        }
    }
}

// ---------------- Kernel 6: penalty + batch ----------------
__global__ __launch_bounds__(256) void k_final(const float* __restrict__ pen,
                                               float* __restrict__ out) {
    const int t = threadIdx.x;
    float s = 0.f;
#pragma unroll
    for (int r = 0; r < 2; ++r) {
        const int i = t + 256 * r;
        float d = pen[i] - 1.f;
        s += d * d;
        out[OFF_BATCH + i] = (float)(i >> 4);
    }
#pragma unroll
    for (int off = 32; off > 0; off >>= 1) s += __shfl_down(s, off, 64);
    __shared__ float ps[4];
    if ((t & 63) == 0) ps[t >> 6] = s;
    __syncthreads();
    if (t == 0) out[OFF_PEN] = (ps[0] + ps[1] + ps[2] + ps[3]) * (1.f / 512.f);
}

extern "C" void kernel_launch(void* const* d_in, const int* in_sizes, int n_in,
                              void* d_out, int out_size, void* d_ws, size_t ws_size,
                              hipStream_t stream) {
    const float* x  = (const float*)d_in[0];
    const float* w1 = (const float*)d_in[1];
    const float* b1 = (const float*)d_in[2];
    const float* w2 = (const float*)d_in[3];
    const float* b2 = (const float*)d_in[4];
    const float* wv = (const float*)d_in[5];
    const float* bv = (const float*)d_in[6];
    float* out = (float*)d_out;

    float* xmean = (float*)d_ws;          // BB*CC
    float* pen   = xmean + BB * CC;       // BB*NH
    float* S     = pen + BB * NH;         // BB*NH*CC

    // zero the atomic accumulator (pen only; S is fully overwritten)
    hipMemsetAsync(pen, 0, (size_t)(BB * NH) * sizeof(float), stream);

    k_mean<<<BB * CC, 256, 0, stream>>>(x, xmean);
    k_mlp<<<BB, 256, 0, stream>>>(xmean, w1, b1, w2, b2, out);
    k_attn<<<dim3(NN / 256, BB), 256, 0, stream>>>(out, pen);
    k_S2<<<1024, 256, 0, stream>>>(x, out, S);
    k_gemm<<<dim3(8, 16), 256, 0, stream>>>(S, wv, bv, pen, out);
    k_final<<<1, 256, 0, stream>>>(pen, out);
}

// Round 3
// 268.149 us; speedup vs baseline: 2.6231x; 1.0201x over previous
//
#include <hip/hip_runtime.h>
#include <math.h>

#define BB 32
#define CC 512
#define NN 4096
#define EMB 1024
#define NH 16

// d_out layout (floats): values | pos | batch | attention | penalty
#define OFF_POS   (BB*NH*EMB)             // 524288
#define OFF_BATCH (OFF_POS + BB*NH*2)     // 525312
#define OFF_ATTN  (OFF_BATCH + BB*NH)     // 525824
#define OFF_PEN   (OFF_ATTN + BB*NN*NH)   // 2622976

// ---------------- Kernel 1: x_mean[b,c] = mean over N of x[b,c,:]  (+ zero pen) ----------------
__global__ __launch_bounds__(256) void k_mean(const float* __restrict__ x,
                                              float* __restrict__ xmean,
                                              float* __restrict__ pen) {
    const size_t row = blockIdx.x;            // b*CC + c
    const int t = threadIdx.x;
    if (blockIdx.x == 0) {                    // zero the atomic accumulator (before k_attn launches)
        pen[t] = 0.f;
        pen[t + 256] = 0.f;
    }
    const float4* xr = (const float4*)(x + row * NN);
    float s = 0.f;
#pragma unroll
    for (int k = 0; k < 4; ++k) {
        float4 v = xr[t + 256 * k];
        s += (v.x + v.y) + (v.z + v.w);
    }
#pragma unroll
    for (int off = 32; off > 0; off >>= 1) s += __shfl_down(s, off, 64);
    __shared__ float ps[4];
    if ((t & 63) == 0) ps[t >> 6] = s;
    __syncthreads();
    if (t == 0) xmean[row] = (ps[0] + ps[1] + ps[2] + ps[3]) * (1.0f / NN);
}

// ---------------- Kernel 2: MLP -> pos (written to d_out pos region) ----------------
__global__ __launch_bounds__(256) void k_mlp(const float* __restrict__ xmean,
                                             const float* __restrict__ w1,
                                             const float* __restrict__ b1,
                                             const float* __restrict__ w2,
                                             const float* __restrict__ b2,
                                             float* __restrict__ out) {
    const int b = blockIdx.x;
    const int t = threadIdx.x;
    __shared__ __align__(16) float xm[CC];
    __shared__ __align__(16) float hid[EMB];
    xm[t]       = xmean[b * CC + t];
    xm[t + 256] = xmean[b * CC + t + 256];
    __syncthreads();
#pragma unroll
    for (int eo = 0; eo < 4; ++eo) {
        const int e = t + eo * 256;
        const float4* wr = (const float4*)(w1 + (size_t)e * CC);
        const float4* xv = (const float4*)xm;
        float acc = 0.f;
        for (int c4 = 0; c4 < CC / 4; ++c4) {
            float4 w = wr[c4]; float4 xx = xv[c4];
            acc += w.x * xx.x + w.y * xx.y + w.z * xx.z + w.w * xx.w;
        }
        acc += b1[e];
        hid[e] = acc / (1.f + expf(-acc));   // silu
    }
    __syncthreads();
    if (t < 2 * NH) {
        const float4* wr = (const float4*)(w2 + (size_t)t * EMB);
        const float4* hv = (const float4*)hid;
        float acc = 0.f;
        for (int e4 = 0; e4 < EMB / 4; ++e4) {
            float4 w = wr[e4]; float4 hh = hv[e4];
            acc += w.x * hh.x + w.y * hh.y + w.z * hh.z + w.w * hh.w;
        }
        acc += b2[t];
        out[OFF_POS + b * 2 * NH + t] = 31.f / (1.f + expf(-acc));  // 31*sigmoid
    }
}

// ---------------- Kernel 3: attention + pen ----------------
__global__ __launch_bounds__(256) void k_attn(float* __restrict__ out,
                                              float* __restrict__ pen) {
    const int b = blockIdx.y;
    const int n0 = blockIdx.x * 256;
    const int t = threadIdx.x;
    __shared__ float pp[2 * NH];
    if (t < 2 * NH) pp[t] = out[OFF_POS + b * 2 * NH + t];
    __syncthreads();
    const int n = n0 + t;
    const float fi = (float)(n >> 6);
    const float fj = (float)(n & 63);
    const float norm = 0.017683882565766149f;   // 1/(2*pi*9)
    float a[NH];
#pragma unroll
    for (int h = 0; h < NH; ++h) {
        float dx = fi - pp[2 * h];
        float dy = fj - pp[2 * h + 1];
        a[h] = norm * expf((dx * dx + dy * dy) * (-1.f / 18.f));
    }
    float4* dst = (float4*)(out + OFF_ATTN + ((size_t)b * NN + n) * NH);
#pragma unroll
    for (int q = 0; q < 4; ++q)
        dst[q] = make_float4(a[4 * q], a[4 * q + 1], a[4 * q + 2], a[4 * q + 3]);
#pragma unroll
    for (int h = 0; h < NH; ++h) {
        float s = a[h];
#pragma unroll
        for (int off = 32; off > 0; off >>= 1) s += __shfl_down(s, off, 64);
        if ((t & 63) == 0) atomicAdd(&pen[b * NH + h], s);
    }
}

// ---------------- Kernel 4: S[b,h,c] = sum_n attn[b,n,h] * x[b,c,n] ----------------
// lane -> n (coalesced x reads); wave -> 4 channels x 16 heads in registers;
// block = (b, 16-channel chunk) over full n; attn chunk staged transposed in LDS.
__global__ __launch_bounds__(256, 4) void k_S2(const float* __restrict__ x,
                                               const float* __restrict__ out,
                                               float* __restrict__ S) {
    // XCD swizzle: cluster the 32 same-b blocks onto one XCD for attn L2 reuse
    const int hwid = blockIdx.x;                 // 0..1023
    const int wgid = (hwid & 7) * 128 + (hwid >> 3);
    const int b  = wgid >> 5;
    const int c0 = (wgid & 31) * 16;
    const int t = threadIdx.x;
    const int w = t >> 6, lane = t & 63;
    const int cbase = c0 + w * 4;

    __shared__ float aT[NH][260];                // transposed attn chunk, pad 4

    float acc[4][NH];
#pragma unroll
    for (int i = 0; i < 4; ++i)
#pragma unroll
        for (int h = 0; h < NH; ++h) acc[i][h] = 0.f;

    const float* xb = x + ((size_t)b * CC + cbase) * NN;
    const float4* asrc = (const float4*)(out + OFF_ATTN + (size_t)b * NN * NH);

    for (int nc = 0; nc < 16; ++nc) {
        const int n0 = nc * 256;
        __syncthreads();                         // aT reuse guard
        // stage attn[n0:n0+256][16] -> aT[h][n] (transposed)
#pragma unroll
        for (int k = 0; k < 4; ++k) {
            const int i = t + 256 * k;           // float4 index within chunk
            float4 v = asrc[n0 * 4 + i];
            const int n = i >> 2, h0 = (i & 3) * 4;
            aT[h0][n] = v.x; aT[h0 + 1][n] = v.y; aT[h0 + 2][n] = v.z; aT[h0 + 3][n] = v.w;
        }
        __syncthreads();
        float4 xv[4];
#pragma unroll
        for (int i = 0; i < 4; ++i)
            xv[i] = *(const float4*)(xb + (size_t)i * NN + n0 + 4 * lane);
#pragma unroll
        for (int h = 0; h < NH; ++h) {
            float4 a = *(const float4*)&aT[h][4 * lane];
#pragma unroll
            for (int i = 0; i < 4; ++i)
                acc[i][h] += a.x * xv[i].x + a.y * xv[i].y + a.z * xv[i].z + a.w * xv[i].w;
        }
    }
    // cross-lane reduction over n
#pragma unroll
    for (int i = 0; i < 4; ++i)
#pragma unroll
        for (int h = 0; h < NH; ++h) {
            float s = acc[i][h];
#pragma unroll
            for (int off = 32; off > 0; off >>= 1) s += __shfl_down(s, off, 64);
            acc[i][h] = s;
        }
    if (lane == 0) {
#pragma unroll
        for (int i = 0; i < 4; ++i)
#pragma unroll
            for (int h = 0; h < NH; ++h)
                S[((size_t)b * NH + h) * CC + cbase + i] = acc[i][h];
    }
}

// ---------------- Kernel 5: values = S @ wv^T + pen*bv ----------------
__global__ __launch_bounds__(256) void k_gemm(const float* __restrict__ S,
                                              const float* __restrict__ wv,
                                              const float* __restrict__ bv,
                                              const float* __restrict__ pen,
                                              float* __restrict__ out) {
    const int m0 = blockIdx.x * 64;   // over B*NH = 512
    const int n0 = blockIdx.y * 64;   // over EMB = 1024
    const int t = threadIdx.x;
    const int tx = t & 15, ty = t >> 4;
    __shared__ float As[64][33];
    __shared__ float Bs[64][33];
    float acc[4][4];
#pragma unroll
    for (int mi = 0; mi < 4; ++mi)
#pragma unroll
        for (int ni = 0; ni < 4; ++ni) acc[mi][ni] = 0.f;
    for (int k0 = 0; k0 < CC; k0 += 32) {
#pragma unroll
        for (int l = 0; l < 2; ++l) {
            const int fi = t + l * 256;
            const int row = fi >> 3, c4 = (fi & 7) * 4;
            float4 va = *(const float4*)(S + (size_t)(m0 + row) * CC + k0 + c4);
            As[row][c4] = va.x; As[row][c4+1] = va.y; As[row][c4+2] = va.z; As[row][c4+3] = va.w;
            float4 vb = *(const float4*)(wv + (size_t)(n0 + row) * CC + k0 + c4);
            Bs[row][c4] = vb.x; Bs[row][c4+1] = vb.y; Bs[row][c4+2] = vb.z; Bs[row][c4+3] = vb.w;
        }
        __syncthreads();
#pragma unroll
        for (int k = 0; k < 32; ++k) {
            float a[4], bb[4];
#pragma unroll
            for (int mi = 0; mi < 4; ++mi) a[mi] = As[ty + 16 * mi][k];
#pragma unroll
            for (int ni = 0; ni < 4; ++ni) bb[ni] = Bs[tx + 16 * ni][k];
#pragma unroll
            for (int mi = 0; mi < 4; ++mi)
#pragma unroll
                for (int ni = 0; ni < 4; ++ni) acc[mi][ni] += a[mi] * bb[ni];
        }
        __syncthreads();
    }
#pragma unroll
    for (int mi = 0; mi < 4; ++mi) {
        const int m = m0 + ty + 16 * mi;
        const float pm = pen[m];
#pragma unroll
        for (int ni = 0; ni < 4; ++ni) {
            const int nn = n0 + tx + 16 * ni;
            out[(size_t)m * EMB + nn] = acc[mi][ni] + pm * bv[nn];
        }
    }
}

// ---------------- Kernel 6: penalty + batch ----------------
__global__ __launch_bounds__(256) void k_final(const float* __restrict__ pen,
                                               float* __restrict__ out) {
    const int t = threadIdx.x;
    float s = 0.f;
#pragma unroll
    for (int r = 0; r < 2; ++r) {
        const int i = t + 256 * r;
        float d = pen[i] - 1.f;
        s += d * d;
        out[OFF_BATCH + i] = (float)(i >> 4);
    }
#pragma unroll
    for (int off = 32; off > 0; off >>= 1) s += __shfl_down(s, off, 64);
    __shared__ float ps[4];
    if ((t & 63) == 0) ps[t >> 6] = s;
    __syncthreads();
    if (t == 0) out[OFF_PEN] = (ps[0] + ps[1] + ps[2] + ps[3]) * (1.f / 512.f);
}

extern "C" void kernel_launch(void* const* d_in, const int* in_sizes, int n_in,
                              void* d_out, int out_size, void* d_ws, size_t ws_size,
                              hipStream_t stream) {
    const float* x  = (const float*)d_in[0];
    const float* w1 = (const float*)d_in[1];
    const float* b1 = (const float*)d_in[2];
    const float* w2 = (const float*)d_in[3];
    const float* b2 = (const float*)d_in[4];
    const float* wv = (const float*)d_in[5];
    const float* bv = (const float*)d_in[6];
    float* out = (float*)d_out;

    float* xmean = (float*)d_ws;          // BB*CC
    float* pen   = xmean + BB * CC;       // BB*NH (zeroed by k_mean block 0)
    float* S     = pen + BB * NH;         // BB*NH*CC

    k_mean<<<BB * CC, 256, 0, stream>>>(x, xmean, pen);
    k_mlp<<<BB, 256, 0, stream>>>(xmean, w1, b1, w2, b2, out);
    k_attn<<<dim3(NN / 256, BB), 256, 0, stream>>>(out, pen);
    k_S2<<<1024, 256, 0, stream>>>(x, out, S);
    k_gemm<<<dim3(8, 16), 256, 0, stream>>>(S, wv, bv, pen, out);
    k_final<<<1, 256, 0, stream>>>(pen, out);
}

// Round 4
// 246.874 us; speedup vs baseline: 2.8491x; 1.0862x over previous
//
#include <hip/hip_runtime.h>
#include <math.h>

#define BB 32
#define CC 512
#define NN 4096
#define EMB 1024
#define NH 16

// d_out layout (floats): values | pos | batch | attention | penalty
#define OFF_POS   (BB*NH*EMB)             // 524288
#define OFF_BATCH (OFF_POS + BB*NH*2)     // 525312
#define OFF_ATTN  (OFF_BATCH + BB*NH)     // 525824
#define OFF_PEN   (OFF_ATTN + BB*NN*NH)   // 2622976

// ---------------- Kernel 1: x_mean[b,c] = mean over N of x[b,c,:]  (+ zero pen) ----------------
__global__ __launch_bounds__(256) void k_mean(const float* __restrict__ x,
                                              float* __restrict__ xmean,
                                              float* __restrict__ pen) {
    const size_t row = blockIdx.x;            // b*CC + c
    const int t = threadIdx.x;
    if (blockIdx.x == 0) {                    // zero atomic accumulator (k_attn is 3 launches later)
        pen[t] = 0.f;
        pen[t + 256] = 0.f;
    }
    const float4* xr = (const float4*)(x + row * NN);
    float s = 0.f;
#pragma unroll
    for (int k = 0; k < 4; ++k) {
        float4 v = xr[t + 256 * k];
        s += (v.x + v.y) + (v.z + v.w);
    }
#pragma unroll
    for (int off = 32; off > 0; off >>= 1) s += __shfl_down(s, off, 64);
    __shared__ float ps[4];
    if ((t & 63) == 0) ps[t >> 6] = s;
    __syncthreads();
    if (t == 0) xmean[row] = (ps[0] + ps[1] + ps[2] + ps[3]) * (1.0f / NN);
}

// ---------------- Kernel 2a: hid[b][e] = silu(w1[e,:] . xmean[b,:] + b1[e]) ----------------
// 128 blocks: (b, quarter). Each thread owns one e-row; 4 independent FMA chains.
__global__ __launch_bounds__(256) void k_mlp_h(const float* __restrict__ xmean,
                                               const float* __restrict__ w1,
                                               const float* __restrict__ b1,
                                               float* __restrict__ hid) {
    const int b = blockIdx.x >> 2;
    const int e = (blockIdx.x & 3) * 256 + threadIdx.x;
    const int t = threadIdx.x;
    __shared__ __align__(16) float xm[CC];
    xm[t]       = xmean[b * CC + t];
    xm[t + 256] = xmean[b * CC + t + 256];
    __syncthreads();
    const float4* wr = (const float4*)(w1 + (size_t)e * CC);
    const float4* xv = (const float4*)xm;
    float4 a4 = make_float4(0.f, 0.f, 0.f, 0.f);
    for (int c4 = 0; c4 < CC / 4; ++c4) {
        float4 w = wr[c4]; float4 xx = xv[c4];
        a4.x += w.x * xx.x; a4.y += w.y * xx.y; a4.z += w.z * xx.z; a4.w += w.w * xx.w;
    }
    float acc = (a4.x + a4.y) + (a4.z + a4.w) + b1[e];
    hid[(size_t)b * EMB + e] = acc / (1.f + expf(-acc));   // silu
}

// ---------------- Kernel 2b: pos = 31*sigmoid(w2 @ hid + b2) ----------------
__global__ __launch_bounds__(256) void k_pos(const float* __restrict__ hid,
                                             const float* __restrict__ w2,
                                             const float* __restrict__ b2,
                                             float* __restrict__ out) {
    const int b = blockIdx.x;
    const int t = threadIdx.x;
    __shared__ __align__(16) float hl[EMB];
#pragma unroll
    for (int k = 0; k < 4; ++k) hl[t + 256 * k] = hid[(size_t)b * EMB + t + 256 * k];
    __syncthreads();
    const int o = t >> 3;          // 0..31
    const int seg = t & 7;         // 8-way split of E
    const float4* wr = (const float4*)(w2 + (size_t)o * EMB + seg * 128);
    const float4* hv = (const float4*)(hl + seg * 128);
    float acc = 0.f;
#pragma unroll
    for (int e4 = 0; e4 < 32; ++e4) {
        float4 w = wr[e4]; float4 hh = hv[e4];
        acc += w.x * hh.x + w.y * hh.y + w.z * hh.z + w.w * hh.w;
    }
    acc += __shfl_down(acc, 4, 64);
    acc += __shfl_down(acc, 2, 64);
    acc += __shfl_down(acc, 1, 64);
    if (seg == 0) {
        acc += b2[o];
        out[OFF_POS + b * 2 * NH + o] = 31.f / (1.f + expf(-acc));
    }
}

// ---------------- Kernel 3: attention (n-major to d_out, h-major to ws) + pen ----------------
__global__ __launch_bounds__(256) void k_attn(float* __restrict__ out,
                                              float* __restrict__ attnT,
                                              float* __restrict__ pen) {
    const int b = blockIdx.y;
    const int n0 = blockIdx.x * 256;
    const int t = threadIdx.x;
    __shared__ float pp[2 * NH];
    if (t < 2 * NH) pp[t] = out[OFF_POS + b * 2 * NH + t];
    __syncthreads();
    const int n = n0 + t;
    const float fi = (float)(n >> 6);
    const float fj = (float)(n & 63);
    const float norm = 0.017683882565766149f;   // 1/(2*pi*9)
    float a[NH];
#pragma unroll
    for (int h = 0; h < NH; ++h) {
        float dx = fi - pp[2 * h];
        float dy = fj - pp[2 * h + 1];
        a[h] = norm * expf((dx * dx + dy * dy) * (-1.f / 18.f));
    }
    float4* dst = (float4*)(out + OFF_ATTN + ((size_t)b * NN + n) * NH);
#pragma unroll
    for (int q = 0; q < 4; ++q)
        dst[q] = make_float4(a[4 * q], a[4 * q + 1], a[4 * q + 2], a[4 * q + 3]);
#pragma unroll
    for (int h = 0; h < NH; ++h)
        attnT[((size_t)b * NH + h) * NN + n] = a[h];   // coalesced per-h
#pragma unroll
    for (int h = 0; h < NH; ++h) {
        float s = a[h];
#pragma unroll
        for (int off = 32; off > 0; off >>= 1) s += __shfl_down(s, off, 64);
        if ((t & 63) == 0) atomicAdd(&pen[b * NH + h], s);
    }
}

// ---------------- Kernel 4: S[b,h,c] = sum_n attnT[b,h,n] * x[b,c,n] ----------------
// No LDS, no barriers: lane -> n (both streams coalesced), wave -> 4 channels x 16 heads.
__global__ __launch_bounds__(256, 4) void k_S3(const float* __restrict__ x,
                                               const float* __restrict__ attnT,
                                               float* __restrict__ S) {
    // XCD swizzle: cluster the 32 same-b blocks onto one XCD for attnT L2 reuse
    const int hwid = blockIdx.x;                 // 0..1023
    const int wgid = (hwid & 7) * 128 + (hwid >> 3);
    const int b  = wgid >> 5;
    const int c0 = (wgid & 31) * 16;
    const int t = threadIdx.x;
    const int w = t >> 6, lane = t & 63;
    const int cbase = c0 + w * 4;

    float acc[4][NH];
#pragma unroll
    for (int i = 0; i < 4; ++i)
#pragma unroll
        for (int h = 0; h < NH; ++h) acc[i][h] = 0.f;

    const float* xb = x + ((size_t)b * CC + cbase) * NN + 4 * lane;
    const float* ab = attnT + (size_t)b * NH * NN + 4 * lane;

#pragma unroll 1
    for (int nc = 0; nc < 16; ++nc) {
        const int n0 = nc * 256;
        float4 xv[4];
#pragma unroll
        for (int i = 0; i < 4; ++i)
            xv[i] = *(const float4*)(xb + (size_t)i * NN + n0);
#pragma unroll
        for (int h = 0; h < NH; ++h) {
            float4 a = *(const float4*)(ab + (size_t)h * NN + n0);
#pragma unroll
            for (int i = 0; i < 4; ++i)
                acc[i][h] += a.x * xv[i].x + a.y * xv[i].y + a.z * xv[i].z + a.w * xv[i].w;
        }
    }
    // cross-lane reduction over n
#pragma unroll
    for (int i = 0; i < 4; ++i)
#pragma unroll
        for (int h = 0; h < NH; ++h) {
            float s = acc[i][h];
#pragma unroll
            for (int off = 32; off > 0; off >>= 1) s += __shfl_down(s, off, 64);
            acc[i][h] = s;
        }
    if (lane == 0) {
#pragma unroll
        for (int i = 0; i < 4; ++i)
#pragma unroll
            for (int h = 0; h < NH; ++h)
                S[((size_t)b * NH + h) * CC + cbase + i] = acc[i][h];
    }
}

// ---------------- Kernel 5: values = S @ wv^T + pen*bv  (32x64 tiles, 256 blocks) ----------------
__global__ __launch_bounds__(256) void k_gemm(const float* __restrict__ S,
                                              const float* __restrict__ wv,
                                              const float* __restrict__ bv,
                                              const float* __restrict__ pen,
                                              float* __restrict__ out) {
    const int m0 = blockIdx.x * 32;   // over B*NH = 512
    const int n0 = blockIdx.y * 64;   // over EMB = 1024
    const int t = threadIdx.x;
    const int tx = t & 15, ty = t >> 4;
    __shared__ float As[32][33];
    __shared__ float Bs[64][33];
    float acc[2][4];
#pragma unroll
    for (int mi = 0; mi < 2; ++mi)
#pragma unroll
        for (int ni = 0; ni < 4; ++ni) acc[mi][ni] = 0.f;
    const int lr = t >> 3, lc = (t & 7) * 4;
    for (int k0 = 0; k0 < CC; k0 += 32) {
        {
            float4 va = *(const float4*)(S + (size_t)(m0 + lr) * CC + k0 + lc);
            As[lr][lc] = va.x; As[lr][lc+1] = va.y; As[lr][lc+2] = va.z; As[lr][lc+3] = va.w;
            float4 vb = *(const float4*)(wv + (size_t)(n0 + lr) * CC + k0 + lc);
            Bs[lr][lc] = vb.x; Bs[lr][lc+1] = vb.y; Bs[lr][lc+2] = vb.z; Bs[lr][lc+3] = vb.w;
            float4 vc = *(const float4*)(wv + (size_t)(n0 + 32 + lr) * CC + k0 + lc);
            Bs[32+lr][lc] = vc.x; Bs[32+lr][lc+1] = vc.y; Bs[32+lr][lc+2] = vc.z; Bs[32+lr][lc+3] = vc.w;
        }
        __syncthreads();
#pragma unroll
        for (int k = 0; k < 32; ++k) {
            float a[2], bb[4];
            a[0] = As[ty][k]; a[1] = As[ty + 16][k];
#pragma unroll
            for (int ni = 0; ni < 4; ++ni) bb[ni] = Bs[tx + 16 * ni][k];
#pragma unroll
            for (int mi = 0; mi < 2; ++mi)
#pragma unroll
                for (int ni = 0; ni < 4; ++ni) acc[mi][ni] += a[mi] * bb[ni];
        }
        __syncthreads();
    }
#pragma unroll
    for (int mi = 0; mi < 2; ++mi) {
        const int m = m0 + ty + 16 * mi;
        const float pm = pen[m];
#pragma unroll
        for (int ni = 0; ni < 4; ++ni) {
            const int nn = n0 + tx + 16 * ni;
            out[(size_t)m * EMB + nn] = acc[mi][ni] + pm * bv[nn];
        }
    }
}

// ---------------- Kernel 6: penalty + batch ----------------
__global__ __launch_bounds__(256) void k_final(const float* __restrict__ pen,
                                               float* __restrict__ out) {
    const int t = threadIdx.x;
    float s = 0.f;
#pragma unroll
    for (int r = 0; r < 2; ++r) {
        const int i = t + 256 * r;
        float d = pen[i] - 1.f;
        s += d * d;
        out[OFF_BATCH + i] = (float)(i >> 4);
    }
#pragma unroll
    for (int off = 32; off > 0; off >>= 1) s += __shfl_down(s, off, 64);
    __shared__ float ps[4];
    if ((t & 63) == 0) ps[t >> 6] = s;
    __syncthreads();
    if (t == 0) out[OFF_PEN] = (ps[0] + ps[1] + ps[2] + ps[3]) * (1.f / 512.f);
}

extern "C" void kernel_launch(void* const* d_in, const int* in_sizes, int n_in,
                              void* d_out, int out_size, void* d_ws, size_t ws_size,
                              hipStream_t stream) {
    const float* x  = (const float*)d_in[0];
    const float* w1 = (const float*)d_in[1];
    const float* b1 = (const float*)d_in[2];
    const float* w2 = (const float*)d_in[3];
    const float* b2 = (const float*)d_in[4];
    const float* wv = (const float*)d_in[5];
    const float* bv = (const float*)d_in[6];
    float* out = (float*)d_out;

    float* xmean = (float*)d_ws;            // 16384
    float* pen   = xmean + BB * CC;         // 512 (zeroed by k_mean block 0)
    float* S     = pen + BB * NH;           // 262144
    float* hid   = S + BB * NH * CC;        // 32768
    float* attnT = hid + BB * EMB;          // 2097152

    k_mean<<<BB * CC, 256, 0, stream>>>(x, xmean, pen);
    k_mlp_h<<<BB * 4, 256, 0, stream>>>(xmean, w1, b1, hid);
    k_pos<<<BB, 256, 0, stream>>>(hid, w2, b2, out);
    k_attn<<<dim3(NN / 256, BB), 256, 0, stream>>>(out, attnT, pen);
    k_S3<<<1024, 256, 0, stream>>>(x, attnT, S);
    k_gemm<<<dim3(16, 16), 256, 0, stream>>>(S, wv, bv, pen, out);
    k_final<<<1, 256, 0, stream>>>(pen, out);
}